// Round 8
// baseline (176.695 us; speedup 1.0000x reference)
//
#include <hip/hip_runtime.h>
#include <hip/hip_bf16.h>

#define T_SEQ 2048
#define D_DIM 1024
#define NB 4

typedef __attribute__((ext_vector_type(8))) short short8;
typedef __attribute__((ext_vector_type(4))) float f32x4;

__device__ __forceinline__ unsigned short f2bf(float f) {
    unsigned int u = __float_as_uint(f);
    u = (u + 0x7FFFu + ((u >> 16) & 1u)) >> 16;
    return (unsigned short)u;
}

__global__ void cast_kernel(const float4* __restrict__ in, ushort4* __restrict__ out, int n4) {
    int i = blockIdx.x * 256 + threadIdx.x;
    if (i < n4) {
        float4 f = in[i];
        ushort4 o;
        o.x = f2bf(f.x); o.y = f2bf(f.y); o.z = f2bf(f.z); o.w = f2bf(f.w);
        out[i] = o;
    }
}

// Wq|Wk|Wv in one launch: grid 3072, 1024 blocks per weight (262144 float4 each).
__global__ void cast3_kernel(const float4* __restrict__ wq, const float4* __restrict__ wk,
                             const float4* __restrict__ wv, ushort4* __restrict__ out) {
    const int w = blockIdx.x >> 10;
    const int i = (blockIdx.x & 1023) * 256 + threadIdx.x;   // < 262144
    const float4* src = (w == 0) ? wq : (w == 1) ? wk : wv;
    float4 f = src[i];
    ushort4 o;
    o.x = f2bf(f.x); o.y = f2bf(f.y); o.z = f2bf(f.z); o.w = f2bf(f.w);
    out[w * 262144 + i] = o;
}

#define GLD(gp, lp) __builtin_amdgcn_global_load_lds( \
    (__attribute__((address_space(1))) void*)(gp), \
    (__attribute__((address_space(3))) void*)(lp), 16, 0, 0)

#define MFMA_BF16 __builtin_amdgcn_mfma_f32_16x16x32_bf16

// ===========================================================================
// 8-phase 256x256 QK projection (r7, proven): BM=BN=256, BK=64, 8 waves,
// wave-tile 128x64.  See r7 notes; unchanged.
// ===========================================================================
#define LIDX(slot, ab, half, ks) ((((((slot)*2 + (ab))*2 + (half))*2 + (ks)) * 4096))

__global__ __launch_bounds__(512, 2) void qk_gemm256(const unsigned short* __restrict__ xb,
                                                     const unsigned short* __restrict__ wb,
                                                     unsigned short* __restrict__ Qb,
                                                     unsigned short* __restrict__ Kb) {
    __shared__ __align__(16) unsigned short L[16 * 4096];   // 128 KiB
    const int tid  = threadIdx.x;
    const int lane = tid & 63;
    const int wave = tid >> 6;
    const int wm   = wave >> 2;
    const int wn   = wave & 3;
    const int bh   = wn >> 1;
    const int lo   = lane & 15;
    const int hi   = lane >> 4;

    const int wg  = (blockIdx.x & 7) * 32 + (blockIdx.x >> 3);
    const int bmA = wg >> 3;
    const int bnB = wg & 7;

    const int srow   = tid >> 2;
    const int schoff = (((tid & 3) ^ ((srow >> 1) & 3)) << 3);
    const unsigned short* sA0 = xb + (size_t)(bmA * 256 +       srow) * 1024 + schoff;
    const unsigned short* sA1 = xb + (size_t)(bmA * 256 + 128 + srow) * 1024 + schoff;
    const unsigned short* sB0 = wb + (size_t)(bnB * 256 +       srow) * 1024 + schoff;
    const unsigned short* sB1 = wb + (size_t)(bnB * 256 + 128 + srow) * 1024 + schoff;
    const int dst8 = tid * 8;

    const int choff  = ((hi ^ ((lo >> 1) & 3)) << 3);
    const int alocal = lo * 32 + choff;
    const int blocal = ((wn & 1) * 64 + lo) * 32 + choff;

    f32x4 acc[8][4] = {};

    GLD(sA0,       &L[LIDX(0,0,0,0) + dst8]);  GLD(sA1,       &L[LIDX(0,0,1,0) + dst8]);
    GLD(sB0,       &L[LIDX(0,1,0,0) + dst8]);  GLD(sB1,       &L[LIDX(0,1,1,0) + dst8]);
    GLD(sA0 + 32,  &L[LIDX(0,0,0,1) + dst8]);  GLD(sA1 + 32,  &L[LIDX(0,0,1,1) + dst8]);
    GLD(sB0 + 32,  &L[LIDX(0,1,0,1) + dst8]);  GLD(sB1 + 32,  &L[LIDX(0,1,1,1) + dst8]);
    GLD(sA0 + 64,  &L[LIDX(1,0,0,0) + dst8]);  GLD(sA1 + 64,  &L[LIDX(1,0,1,0) + dst8]);
    GLD(sB0 + 64,  &L[LIDX(1,1,0,0) + dst8]);  GLD(sB1 + 64,  &L[LIDX(1,1,1,0) + dst8]);
    asm volatile("s_waitcnt vmcnt(8)" ::: "memory");
    __builtin_amdgcn_s_barrier();

    const int nt = 16;
    for (int t = 0; t < nt; ++t) {
        const int cur = t & 1;
        const unsigned short* Ak0 = &L[LIDX(cur, 0, wm, 0)] + alocal;
        const unsigned short* Bk0 = &L[LIDX(cur, 1, bh, 0)] + blocal;
        const unsigned short* Ak1 = &L[LIDX(cur, 0, wm, 1)] + alocal;
        const unsigned short* Bk1 = &L[LIDX(cur, 1, bh, 1)] + blocal;
        short8 av[4], bv0[4], bv1[4];

        // phase 1: k0, mf0-3
#pragma unroll
        for (int m = 0; m < 4; ++m) av[m]  = *(const short8*)(Ak0 + m * 512);
#pragma unroll
        for (int n = 0; n < 4; ++n) bv0[n] = *(const short8*)(Bk0 + n * 512);
        if (t + 1 < nt) {
            const int ko = (t + 1) * 64 + 32;
            GLD(sA0 + ko, &L[LIDX(cur ^ 1, 0, 0, 1) + dst8]);
            GLD(sA1 + ko, &L[LIDX(cur ^ 1, 0, 1, 1) + dst8]);
        }
        __builtin_amdgcn_s_barrier();
        asm volatile("s_waitcnt lgkmcnt(0)" ::: "memory");
        __builtin_amdgcn_sched_barrier(0);
        __builtin_amdgcn_s_setprio(1);
#pragma unroll
        for (int m = 0; m < 4; ++m)
#pragma unroll
            for (int n = 0; n < 4; ++n)
                acc[m][n] = MFMA_BF16(av[m], bv0[n], acc[m][n], 0, 0, 0);
        __builtin_amdgcn_s_setprio(0);
        __builtin_amdgcn_s_barrier();

        // phase 2: k0, mf4-7
#pragma unroll
        for (int m = 0; m < 4; ++m) av[m] = *(const short8*)(Ak0 + (4 + m) * 512);
        if (t + 1 < nt) {
            const int ko = (t + 1) * 64 + 32;
            GLD(sB0 + ko, &L[LIDX(cur ^ 1, 1, 0, 1) + dst8]);
            GLD(sB1 + ko, &L[LIDX(cur ^ 1, 1, 1, 1) + dst8]);
        }
        if (t + 1 < nt) { asm volatile("s_waitcnt vmcnt(8)" ::: "memory"); }
        else            { asm volatile("s_waitcnt vmcnt(0)" ::: "memory"); }
        __builtin_amdgcn_s_barrier();
        asm volatile("s_waitcnt lgkmcnt(0)" ::: "memory");
        __builtin_amdgcn_sched_barrier(0);
        __builtin_amdgcn_s_setprio(1);
#pragma unroll
        for (int m = 0; m < 4; ++m)
#pragma unroll
            for (int n = 0; n < 4; ++n)
                acc[4 + m][n] = MFMA_BF16(av[m], bv0[n], acc[4 + m][n], 0, 0, 0);
        __builtin_amdgcn_s_setprio(0);
        __builtin_amdgcn_s_barrier();

        // phase 3: k1, mf0-3
#pragma unroll
        for (int m = 0; m < 4; ++m) av[m]  = *(const short8*)(Ak1 + m * 512);
#pragma unroll
        for (int n = 0; n < 4; ++n) bv1[n] = *(const short8*)(Bk1 + n * 512);
        if (t + 2 < nt) {
            const int ko = (t + 2) * 64;
            GLD(sA0 + ko, &L[LIDX(cur, 0, 0, 0) + dst8]);
            GLD(sA1 + ko, &L[LIDX(cur, 0, 1, 0) + dst8]);
        }
        __builtin_amdgcn_s_barrier();
        asm volatile("s_waitcnt lgkmcnt(0)" ::: "memory");
        __builtin_amdgcn_sched_barrier(0);
        __builtin_amdgcn_s_setprio(1);
#pragma unroll
        for (int m = 0; m < 4; ++m)
#pragma unroll
            for (int n = 0; n < 4; ++n)
                acc[m][n] = MFMA_BF16(av[m], bv1[n], acc[m][n], 0, 0, 0);
        __builtin_amdgcn_s_setprio(0);
        __builtin_amdgcn_s_barrier();

        // phase 4: k1, mf4-7
#pragma unroll
        for (int m = 0; m < 4; ++m) av[m] = *(const short8*)(Ak1 + (4 + m) * 512);
        if (t + 2 < nt) {
            const int ko = (t + 2) * 64;
            GLD(sB0 + ko, &L[LIDX(cur, 1, 0, 0) + dst8]);
            GLD(sB1 + ko, &L[LIDX(cur, 1, 1, 0) + dst8]);
        }
        if (t + 1 < nt) {
            if (t + 2 < nt) { asm volatile("s_waitcnt vmcnt(8)" ::: "memory"); }
            else            { asm volatile("s_waitcnt vmcnt(4)" ::: "memory"); }
        }
        __builtin_amdgcn_s_barrier();
        asm volatile("s_waitcnt lgkmcnt(0)" ::: "memory");
        __builtin_amdgcn_sched_barrier(0);
        __builtin_amdgcn_s_setprio(1);
#pragma unroll
        for (int m = 0; m < 4; ++m)
#pragma unroll
            for (int n = 0; n < 4; ++n)
                acc[4 + m][n] = MFMA_BF16(av[m], bv1[n], acc[4 + m][n], 0, 0, 0);
        __builtin_amdgcn_s_setprio(0);
        __builtin_amdgcn_s_barrier();
    }

    unsigned short* O = (bnB < 4) ? Qb : Kb;
    const int rb = bmA * 256 + wm * 128 + hi * 4;
    const int cb = (bnB & 3) * 256 + wn * 64 + lo;
#pragma unroll
    for (int mf = 0; mf < 8; ++mf)
#pragma unroll
        for (int nf = 0; nf < 4; ++nf)
#pragma unroll
            for (int r = 0; r < 4; ++r)
                O[(size_t)(rb + mf * 16 + r) * D_DIM + (cb + nf * 16)] = f2bf(acc[mf][nf][r]);
}

// ---------------------------------------------------------------------------
// 128x128 core (r4, proven): depth-2 prefetch over 3 buffers, counted vmcnt,
// T2 swizzle.
// ---------------------------------------------------------------------------
__device__ __forceinline__ void gemm_core(const unsigned short* __restrict__ A,
                                          const unsigned short* __restrict__ B,
                                          int lda, int ldb, int bm, int bn, int kend,
                                          f32x4 acc[4][4]) {
    __shared__ __align__(16) unsigned short As[3][128 * 32];
    __shared__ __align__(16) unsigned short Bs[3][128 * 32];
    const int tid  = threadIdx.x;
    const int lane = tid & 63;
    const int wave = tid >> 6;
    const int wm   = (wave >> 1) * 64;
    const int wn   = (wave & 1) * 64;
    const int lo   = lane & 15;
    const int hi   = lane >> 4;
    const int r0   = tid >> 2;
    const int q0   = (((tid & 3) ^ ((r0 >> 1) & 3)) * 8);

    const unsigned short* Arow0 = A + (size_t)(bm * 128 + r0) * lda + q0;
    const unsigned short* Arow1 = A + (size_t)(bm * 128 + r0 + 64) * lda + q0;
    const unsigned short* Brow0 = B + (size_t)(bn * 128 + r0) * ldb + q0;
    const unsigned short* Brow1 = B + (size_t)(bn * 128 + r0 + 64) * ldb + q0;

#define STAGE(t, buf) do { const int kk_ = (t) << 5; \
        GLD(Arow0 + kk_, As[buf] + tid * 8); \
        GLD(Arow1 + kk_, As[buf] + (tid + 256) * 8); \
        GLD(Brow0 + kk_, Bs[buf] + tid * 8); \
        GLD(Brow1 + kk_, Bs[buf] + (tid + 256) * 8); } while (0)

    const int nt = kend >> 5;
    STAGE(0, 0);
    STAGE(1, 1);

    int aoff[4], boff[4];
#pragma unroll
    for (int m = 0; m < 4; ++m) {
        const int ra = wm + m * 16 + lo;
        const int rb = wn + m * 16 + lo;
        aoff[m] = ra * 32 + ((hi ^ ((ra >> 1) & 3)) * 8);
        boff[m] = rb * 32 + ((hi ^ ((rb >> 1) & 3)) * 8);
    }

    int cur = 0;
    for (int t = 0; t < nt; ++t) {
        __builtin_amdgcn_s_barrier();
        if (t + 2 < nt) {
            int nb = cur + 2; if (nb >= 3) nb -= 3;
            STAGE(t + 2, nb);
            asm volatile("s_waitcnt vmcnt(8)" ::: "memory");
        } else if (t + 1 < nt) {
            asm volatile("s_waitcnt vmcnt(4)" ::: "memory");
        } else {
            asm volatile("s_waitcnt vmcnt(0)" ::: "memory");
        }
        __builtin_amdgcn_s_barrier();
        __builtin_amdgcn_sched_barrier(0);

        short8 av[4], bv[4];
#pragma unroll
        for (int m = 0; m < 4; ++m) av[m] = *(const short8*)&As[cur][aoff[m]];
#pragma unroll
        for (int n = 0; n < 4; ++n) bv[n] = *(const short8*)&Bs[cur][boff[n]];
        asm volatile("s_waitcnt lgkmcnt(0)" ::: "memory");
        __builtin_amdgcn_sched_barrier(0);

        __builtin_amdgcn_s_setprio(1);
#pragma unroll
        for (int m = 0; m < 4; ++m)
#pragma unroll
            for (int n = 0; n < 4; ++n)
                acc[m][n] = MFMA_BF16(av[m], bv[n], acc[m][n], 0, 0, 0);
        __builtin_amdgcn_s_setprio(0);

        cur += 1; if (cur >= 3) cur = 0;
    }
#undef STAGE
}

// ===========================================================================
// Fused S-scores + V^T projection: 1056 blocks, ONE gemm_core call site
// (shared 48 KB LDS -> 3 blocks/CU), so s-tiles and v-tiles co-reside and
// cross-cover each other's barrier drains.
//   d < 544 : S tile  (A=Q[z], B=K[z], causal triangle decode, K=1024)
//   d >= 544: V^T tile (A=Wv rows=e, B=xb rows=t, K=1024)
// ===========================================================================
__global__ __launch_bounds__(256) void sv_gemm(const unsigned short* __restrict__ Qb,
                                               const unsigned short* __restrict__ Kb,
                                               const unsigned short* __restrict__ xb,
                                               const unsigned short* __restrict__ wv,
                                               float* __restrict__ S,
                                               unsigned short* __restrict__ Vt) {
    const int d = blockIdx.x;
    const unsigned short *Ap, *Bp;
    int bm, bn, z = 0;
    const bool is_s = d < 544;
    if (is_s) {
        const int j = d & 7;
        z = j >> 1;
        int i = (j & 1) * 68 + (d >> 3);
        int bmi = 0;
        while (i >= bmi + 1) { i -= (bmi + 1); ++bmi; }
        bm = bmi; bn = i;
        Ap = Qb + (size_t)z * T_SEQ * D_DIM;
        Bp = Kb + (size_t)z * T_SEQ * D_DIM;
    } else {
        const int e = d - 544;
        bm = e >> 6;          // e-block 0..7
        bn = e & 63;          // t-block 0..63
        Ap = wv;
        Bp = xb;
    }

    f32x4 acc[4][4] = {};
    gemm_core(Ap, Bp, D_DIM, D_DIM, bm, bn, D_DIM, acc);

    const int lane = threadIdx.x & 63, wave = threadIdx.x >> 6;
    const int rb = bm * 128 + (wave >> 1) * 64 + ((lane >> 4) << 2);
    const int cb = bn * 128 + (wave & 1) * 64 + (lane & 15);
    if (is_s) {
        float* Sp = S + (size_t)z * T_SEQ * T_SEQ;
        const float scale = 0.03125f;
#pragma unroll
        for (int m = 0; m < 4; ++m)
#pragma unroll
            for (int n = 0; n < 4; ++n)
#pragma unroll
                for (int r = 0; r < 4; ++r) {
                    int row = rb + m * 16 + r;
                    int col = cb + n * 16;
                    if (col <= row) Sp[(size_t)row * T_SEQ + col] = acc[m][n][r] * scale;
                }
    } else {
#pragma unroll
        for (int m = 0; m < 4; ++m)
#pragma unroll
            for (int n = 0; n < 4; ++n)
#pragma unroll
                for (int r = 0; r < 4; ++r) {
                    const int e = rb + m * 16 + r;       // 0..1023
                    const int t = cb + n * 16;           // 0..8191
                    Vt[((size_t)(t >> 11) * D_DIM + e) * T_SEQ + (t & 2047)] = f2bf(acc[m][n][r]);
                }
    }
}

// Wave-per-row softmax: 4 rows/block, row in registers, shuffle reductions.
__global__ __launch_bounds__(256) void softmax_kernel(const float* __restrict__ S,
                                                      unsigned short* __restrict__ P) {
    const int lane = threadIdx.x & 63, wave = threadIdx.x >> 6;
    const int row = blockIdx.x * 4 + wave;
    const int b = row >> 11, i = row & 2047;
    const float* srow = S + ((size_t)b * T_SEQ + i) * T_SEQ;
    unsigned short* prow = P + ((size_t)b * T_SEQ + i) * T_SEQ;
    const int len = i + 1;
    const int padlen = ((i >> 7) + 1) * 128;

    f32x4 v[8];
    float m = -1e30f;
#pragma unroll
    for (int c = 0; c < 8; ++c) {
        const int j0 = (c * 64 + lane) * 4;
        if (j0 < padlen) {
            v[c] = *(const f32x4*)(srow + j0);
#pragma unroll
            for (int e = 0; e < 4; ++e)
                if (j0 + e < len) m = fmaxf(m, v[c][e]);
        }
    }
#pragma unroll
    for (int off = 32; off; off >>= 1) m = fmaxf(m, __shfl_xor(m, off, 64));

    float s = 0.f;
#pragma unroll
    for (int c = 0; c < 8; ++c) {
        const int j0 = (c * 64 + lane) * 4;
        if (j0 < padlen) {
#pragma unroll
            for (int e = 0; e < 4; ++e) {
                float ev = (j0 + e < len) ? __expf(v[c][e] - m) : 0.f;
                v[c][e] = ev;
                s += ev;
            }
        }
    }
#pragma unroll
    for (int off = 32; off; off >>= 1) s += __shfl_xor(s, off, 64);
    const float inv = 1.f / s;

#pragma unroll
    for (int c = 0; c < 8; ++c) {
        const int j0 = (c * 64 + lane) * 4;
        if (j0 < padlen) {
            ushort4 o;
            o.x = f2bf(v[c][0] * inv);
            o.y = f2bf(v[c][1] * inv);
            o.z = f2bf(v[c][2] * inv);
            o.w = f2bf(v[c][3] * inv);
            *(ushort4*)(prow + j0) = o;
        }
    }
}

// Flat grid of 512; LONGEST-FIRST (bm = 15 - t>>3) so the 64-K-step blocks
// start at t=0 and the short ones pack behind them (kills the straggler tail).
__global__ __launch_bounds__(256) void pv_gemm(const unsigned short* __restrict__ P,
                                               const unsigned short* __restrict__ Vt,
                                               float* __restrict__ Out) {
    const int d = blockIdx.x;
    const int j = d & 7;
    const int z = j >> 1;
    const int t = (j & 1) * 64 + (d >> 3);
    const int bm = 15 - (t >> 3), bn = t & 7;

    const unsigned short* Ap = P + (size_t)z * T_SEQ * T_SEQ;
    const unsigned short* Bp = Vt + (size_t)z * D_DIM * T_SEQ;
    f32x4 acc[4][4] = {};
    gemm_core(Ap, Bp, T_SEQ, T_SEQ, bm, bn, (bm + 1) * 128, acc);

    float* Op = Out + (size_t)z * T_SEQ * D_DIM;
    const int lane = threadIdx.x & 63, wave = threadIdx.x >> 6;
    const int rb = bm * 128 + (wave >> 1) * 64 + ((lane >> 4) << 2);
    const int cb = bn * 128 + (wave & 1) * 64 + (lane & 15);
#pragma unroll
    for (int m = 0; m < 4; ++m)
#pragma unroll
        for (int n = 0; n < 4; ++n)
#pragma unroll
            for (int r = 0; r < 4; ++r)
                Op[(size_t)(rb + m * 16 + r) * D_DIM + (cb + n * 16)] = acc[m][n][r];
}

extern "C" void kernel_launch(void* const* d_in, const int* in_sizes, int n_in,
                              void* d_out, int out_size, void* d_ws, size_t ws_size,
                              hipStream_t stream) {
    const float* x  = (const float*)d_in[0];
    const float* Wq = (const float*)d_in[1];
    const float* Wk = (const float*)d_in[2];
    const float* Wv = (const float*)d_in[3];
    float* out = (float*)d_out;
    char* ws = (char*)d_ws;

    unsigned short* xb = (unsigned short*)(ws);                 // 16 MB  x bf16 [8192,1024]
    unsigned short* wb = (unsigned short*)(ws + 16777216);      // 6 MB   Wq|Wk|Wv bf16
    unsigned short* Qb = (unsigned short*)(ws + 23068672);      // 16 MB
    unsigned short* Kb = (unsigned short*)(ws + 39845888);      // 16 MB
    unsigned short* Vt = (unsigned short*)(ws + 56623104);      // 16 MB  V^T per batch [1024][2048]
    float*          S  = (float*)(ws + 73400320);               // 64 MB  scores fp32
    unsigned short* P  = (unsigned short*)(ws + 140509184);     // 32 MB  probs bf16
    (void)ws_size; (void)in_sizes; (void)n_in; (void)out_size;

    cast_kernel<<<8192, 256, 0, stream>>>((const float4*)x, (ushort4*)xb, 2097152);
    cast3_kernel<<<3072, 256, 0, stream>>>((const float4*)Wq, (const float4*)Wk,
                                           (const float4*)Wv, (ushort4*)wb);

    qk_gemm256<<<256, 512, 0, stream>>>(xb, wb, Qb, Kb);
    sv_gemm<<<1056, 256, 0, stream>>>(Qb, Kb, xb, wb + 2097152, S, Vt);
    softmax_kernel<<<2048, 256, 0, stream>>>(S, P);
    pv_gemm<<<512, 256, 0, stream>>>(P, Vt, out);
}

// Round 9
// 167.353 us; speedup vs baseline: 1.0558x; 1.0558x over previous
//
#include <hip/hip_runtime.h>
#include <hip/hip_bf16.h>

#define T_SEQ 2048
#define D_DIM 1024
#define NB 4

typedef __attribute__((ext_vector_type(8))) short short8;
typedef __attribute__((ext_vector_type(4))) float f32x4;

__device__ __forceinline__ unsigned short f2bf(float f) {
    unsigned int u = __float_as_uint(f);
    u = (u + 0x7FFFu + ((u >> 16) & 1u)) >> 16;
    return (unsigned short)u;
}

__global__ void cast_kernel(const float4* __restrict__ in, ushort4* __restrict__ out, int n4) {
    int i = blockIdx.x * 256 + threadIdx.x;
    if (i < n4) {
        float4 f = in[i];
        ushort4 o;
        o.x = f2bf(f.x); o.y = f2bf(f.y); o.z = f2bf(f.z); o.w = f2bf(f.w);
        out[i] = o;
    }
}

// Wq|Wk|Wv in one launch.
__global__ void cast3_kernel(const float4* __restrict__ wq, const float4* __restrict__ wk,
                             const float4* __restrict__ wv, ushort4* __restrict__ out) {
    const int w = blockIdx.x >> 10;
    const int i = (blockIdx.x & 1023) * 256 + threadIdx.x;
    const float4* src = (w == 0) ? wq : (w == 1) ? wk : wv;
    float4 f = src[i];
    ushort4 o;
    o.x = f2bf(f.x); o.y = f2bf(f.y); o.z = f2bf(f.z); o.w = f2bf(f.w);
    out[w * 262144 + i] = o;
}

#define GLD(gp, lp) __builtin_amdgcn_global_load_lds( \
    (__attribute__((address_space(1))) void*)(gp), \
    (__attribute__((address_space(3))) void*)(lp), 16, 0, 0)

#define MFMA_BF16 __builtin_amdgcn_mfma_f32_16x16x32_bf16

// ===========================================================================
// 8-phase 256x256 core (r7-proven): BM=BN=256, BK=64, 8 waves (2M x 4N),
// wave-tile 128x64, LDS 128 KiB as 16 slices.  A,B row-major [*,1024] bf16,
// B-transposed semantics.  Runs the whole K=1024 loop and leaves acc filled.
// ===========================================================================
#define LIDX(slot, ab, half, ks) ((((((slot)*2 + (ab))*2 + (half))*2 + (ks)) * 4096))

__device__ __forceinline__ void core256(const unsigned short* __restrict__ Ap,
                                        const unsigned short* __restrict__ Bp,
                                        int bmA, int bnB,
                                        unsigned short* __restrict__ L,
                                        f32x4 acc[8][4]) {
    const int tid  = threadIdx.x;
    const int lane = tid & 63;
    const int wave = tid >> 6;
    const int wm   = wave >> 2;
    const int wn   = wave & 3;
    const int bh   = wn >> 1;
    const int lo   = lane & 15;
    const int hi   = lane >> 4;

    const int srow   = tid >> 2;
    const int schoff = (((tid & 3) ^ ((srow >> 1) & 3)) << 3);
    const unsigned short* sA0 = Ap + (size_t)(bmA * 256 +       srow) * 1024 + schoff;
    const unsigned short* sA1 = Ap + (size_t)(bmA * 256 + 128 + srow) * 1024 + schoff;
    const unsigned short* sB0 = Bp + (size_t)(bnB * 256 +       srow) * 1024 + schoff;
    const unsigned short* sB1 = Bp + (size_t)(bnB * 256 + 128 + srow) * 1024 + schoff;
    const int dst8 = tid * 8;

    const int choff  = ((hi ^ ((lo >> 1) & 3)) << 3);
    const int alocal = lo * 32 + choff;
    const int blocal = ((wn & 1) * 64 + lo) * 32 + choff;

    GLD(sA0,       &L[LIDX(0,0,0,0) + dst8]);  GLD(sA1,       &L[LIDX(0,0,1,0) + dst8]);
    GLD(sB0,       &L[LIDX(0,1,0,0) + dst8]);  GLD(sB1,       &L[LIDX(0,1,1,0) + dst8]);
    GLD(sA0 + 32,  &L[LIDX(0,0,0,1) + dst8]);  GLD(sA1 + 32,  &L[LIDX(0,0,1,1) + dst8]);
    GLD(sB0 + 32,  &L[LIDX(0,1,0,1) + dst8]);  GLD(sB1 + 32,  &L[LIDX(0,1,1,1) + dst8]);
    GLD(sA0 + 64,  &L[LIDX(1,0,0,0) + dst8]);  GLD(sA1 + 64,  &L[LIDX(1,0,1,0) + dst8]);
    GLD(sB0 + 64,  &L[LIDX(1,1,0,0) + dst8]);  GLD(sB1 + 64,  &L[LIDX(1,1,1,0) + dst8]);
    asm volatile("s_waitcnt vmcnt(8)" ::: "memory");
    __builtin_amdgcn_s_barrier();

    const int nt = 16;
    for (int t = 0; t < nt; ++t) {
        const int cur = t & 1;
        const unsigned short* Ak0 = &L[LIDX(cur, 0, wm, 0)] + alocal;
        const unsigned short* Bk0 = &L[LIDX(cur, 1, bh, 0)] + blocal;
        const unsigned short* Ak1 = &L[LIDX(cur, 0, wm, 1)] + alocal;
        const unsigned short* Bk1 = &L[LIDX(cur, 1, bh, 1)] + blocal;
        short8 av[4], bv0[4], bv1[4];

        // phase 1: k0, mf0-3
#pragma unroll
        for (int m = 0; m < 4; ++m) av[m]  = *(const short8*)(Ak0 + m * 512);
#pragma unroll
        for (int n = 0; n < 4; ++n) bv0[n] = *(const short8*)(Bk0 + n * 512);
        if (t + 1 < nt) {
            const int ko = (t + 1) * 64 + 32;
            GLD(sA0 + ko, &L[LIDX(cur ^ 1, 0, 0, 1) + dst8]);
            GLD(sA1 + ko, &L[LIDX(cur ^ 1, 0, 1, 1) + dst8]);
        }
        __builtin_amdgcn_s_barrier();
        asm volatile("s_waitcnt lgkmcnt(0)" ::: "memory");
        __builtin_amdgcn_sched_barrier(0);
        __builtin_amdgcn_s_setprio(1);
#pragma unroll
        for (int m = 0; m < 4; ++m)
#pragma unroll
            for (int n = 0; n < 4; ++n)
                acc[m][n] = MFMA_BF16(av[m], bv0[n], acc[m][n], 0, 0, 0);
        __builtin_amdgcn_s_setprio(0);
        __builtin_amdgcn_s_barrier();

        // phase 2: k0, mf4-7
#pragma unroll
        for (int m = 0; m < 4; ++m) av[m] = *(const short8*)(Ak0 + (4 + m) * 512);
        if (t + 1 < nt) {
            const int ko = (t + 1) * 64 + 32;
            GLD(sB0 + ko, &L[LIDX(cur ^ 1, 1, 0, 1) + dst8]);
            GLD(sB1 + ko, &L[LIDX(cur ^ 1, 1, 1, 1) + dst8]);
        }
        if (t + 1 < nt) { asm volatile("s_waitcnt vmcnt(8)" ::: "memory"); }
        else            { asm volatile("s_waitcnt vmcnt(0)" ::: "memory"); }
        __builtin_amdgcn_s_barrier();
        asm volatile("s_waitcnt lgkmcnt(0)" ::: "memory");
        __builtin_amdgcn_sched_barrier(0);
        __builtin_amdgcn_s_setprio(1);
#pragma unroll
        for (int m = 0; m < 4; ++m)
#pragma unroll
            for (int n = 0; n < 4; ++n)
                acc[4 + m][n] = MFMA_BF16(av[m], bv0[n], acc[4 + m][n], 0, 0, 0);
        __builtin_amdgcn_s_setprio(0);
        __builtin_amdgcn_s_barrier();

        // phase 3: k1, mf0-3
#pragma unroll
        for (int m = 0; m < 4; ++m) av[m]  = *(const short8*)(Ak1 + m * 512);
#pragma unroll
        for (int n = 0; n < 4; ++n) bv1[n] = *(const short8*)(Bk1 + n * 512);
        if (t + 2 < nt) {
            const int ko = (t + 2) * 64;
            GLD(sA0 + ko, &L[LIDX(cur, 0, 0, 0) + dst8]);
            GLD(sA1 + ko, &L[LIDX(cur, 0, 1, 0) + dst8]);
        }
        __builtin_amdgcn_s_barrier();
        asm volatile("s_waitcnt lgkmcnt(0)" ::: "memory");
        __builtin_amdgcn_sched_barrier(0);
        __builtin_amdgcn_s_setprio(1);
#pragma unroll
        for (int m = 0; m < 4; ++m)
#pragma unroll
            for (int n = 0; n < 4; ++n)
                acc[m][n] = MFMA_BF16(av[m], bv1[n], acc[m][n], 0, 0, 0);
        __builtin_amdgcn_s_setprio(0);
        __builtin_amdgcn_s_barrier();

        // phase 4: k1, mf4-7
#pragma unroll
        for (int m = 0; m < 4; ++m) av[m] = *(const short8*)(Ak1 + (4 + m) * 512);
        if (t + 2 < nt) {
            const int ko = (t + 2) * 64;
            GLD(sB0 + ko, &L[LIDX(cur, 1, 0, 0) + dst8]);
            GLD(sB1 + ko, &L[LIDX(cur, 1, 1, 0) + dst8]);
        }
        if (t + 1 < nt) {
            if (t + 2 < nt) { asm volatile("s_waitcnt vmcnt(8)" ::: "memory"); }
            else            { asm volatile("s_waitcnt vmcnt(4)" ::: "memory"); }
        }
        __builtin_amdgcn_s_barrier();
        asm volatile("s_waitcnt lgkmcnt(0)" ::: "memory");
        __builtin_amdgcn_sched_barrier(0);
        __builtin_amdgcn_s_setprio(1);
#pragma unroll
        for (int m = 0; m < 4; ++m)
#pragma unroll
            for (int n = 0; n < 4; ++n)
                acc[4 + m][n] = MFMA_BF16(av[m], bv1[n], acc[4 + m][n], 0, 0, 0);
        __builtin_amdgcn_s_setprio(0);
        __builtin_amdgcn_s_barrier();
    }
}

// QK projection on the 8-phase core (r7, proven): grid 256 x 512thr.
__global__ __launch_bounds__(512, 2) void qk_gemm256(const unsigned short* __restrict__ xb,
                                                     const unsigned short* __restrict__ wb,
                                                     unsigned short* __restrict__ Qb,
                                                     unsigned short* __restrict__ Kb) {
    __shared__ __align__(16) unsigned short L[16 * 4096];
    const int lane = threadIdx.x & 63, wave = threadIdx.x >> 6;
    const int wm = wave >> 2, wn = wave & 3;
    const int lo = lane & 15, hi = lane >> 4;

    const int wg  = (blockIdx.x & 7) * 32 + (blockIdx.x >> 3);
    const int bmA = wg >> 3;
    const int bnB = wg & 7;

    f32x4 acc[8][4] = {};
    core256(xb, wb, bmA, bnB, L, acc);

    unsigned short* O = (bnB < 4) ? Qb : Kb;
    const int rb = bmA * 256 + wm * 128 + hi * 4;
    const int cb = (bnB & 3) * 256 + wn * 64 + lo;
#pragma unroll
    for (int mf = 0; mf < 8; ++mf)
#pragma unroll
        for (int nf = 0; nf < 4; ++nf)
#pragma unroll
            for (int r = 0; r < 4; ++r)
                O[(size_t)(rb + mf * 16 + r) * D_DIM + (cb + nf * 16)] = f2bf(acc[mf][nf][r]);
}

// S scores on the 8-phase core: grid 144 = 36 causal 256-tiles x 4 batches.
__global__ __launch_bounds__(512, 2) void s_gemm256(const unsigned short* __restrict__ Qb,
                                                    const unsigned short* __restrict__ Kb,
                                                    float* __restrict__ S) {
    __shared__ __align__(16) unsigned short L[16 * 4096];
    const int lane = threadIdx.x & 63, wave = threadIdx.x >> 6;
    const int wm = wave >> 2, wn = wave & 3;
    const int lo = lane & 15, hi = lane >> 4;

    // bijective XCD swizzle (144 = 8 x 18), then triangle decode.
    const int wg = (blockIdx.x & 7) * 18 + (blockIdx.x >> 3);
    const int z  = wg / 36;
    int i = wg % 36;
    int bm = 0;
    while (i >= bm + 1) { i -= (bm + 1); ++bm; }   // bm 0..7, bn=i<=bm
    const int bn = i;

    const unsigned short* Ap = Qb + (size_t)z * T_SEQ * D_DIM;
    const unsigned short* Bp = Kb + (size_t)z * T_SEQ * D_DIM;
    f32x4 acc[8][4] = {};
    core256(Ap, Bp, bm, bn, L, acc);

    float* Sp = S + (size_t)z * T_SEQ * T_SEQ;
    const float scale = 0.03125f;   // 1/sqrt(1024)
    const int rb = bm * 256 + wm * 128 + hi * 4;
    const int cb = bn * 256 + wn * 64 + lo;
#pragma unroll
    for (int mf = 0; mf < 8; ++mf)
#pragma unroll
        for (int nf = 0; nf < 4; ++nf)
#pragma unroll
            for (int r = 0; r < 4; ++r) {
                const int row = rb + mf * 16 + r;
                const int col = cb + nf * 16;
                if (col <= row) Sp[(size_t)row * T_SEQ + col] = acc[mf][nf][r] * scale;
            }
}

// ---------------------------------------------------------------------------
// 128x128 core (r4, proven): depth-2 prefetch over 3 buffers, counted vmcnt,
// T2 swizzle.  Used by v_gemm / pv_gemm.
// ---------------------------------------------------------------------------
__device__ __forceinline__ void gemm_core(const unsigned short* __restrict__ A,
                                          const unsigned short* __restrict__ B,
                                          int lda, int ldb, int bm, int bn, int kend,
                                          f32x4 acc[4][4]) {
    __shared__ __align__(16) unsigned short As[3][128 * 32];
    __shared__ __align__(16) unsigned short Bs[3][128 * 32];
    const int tid  = threadIdx.x;
    const int lane = tid & 63;
    const int wave = tid >> 6;
    const int wm   = (wave >> 1) * 64;
    const int wn   = (wave & 1) * 64;
    const int lo   = lane & 15;
    const int hi   = lane >> 4;
    const int r0   = tid >> 2;
    const int q0   = (((tid & 3) ^ ((r0 >> 1) & 3)) * 8);

    const unsigned short* Arow0 = A + (size_t)(bm * 128 + r0) * lda + q0;
    const unsigned short* Arow1 = A + (size_t)(bm * 128 + r0 + 64) * lda + q0;
    const unsigned short* Brow0 = B + (size_t)(bn * 128 + r0) * ldb + q0;
    const unsigned short* Brow1 = B + (size_t)(bn * 128 + r0 + 64) * ldb + q0;

#define STAGE(t, buf) do { const int kk_ = (t) << 5; \
        GLD(Arow0 + kk_, As[buf] + tid * 8); \
        GLD(Arow1 + kk_, As[buf] + (tid + 256) * 8); \
        GLD(Brow0 + kk_, Bs[buf] + tid * 8); \
        GLD(Brow1 + kk_, Bs[buf] + (tid + 256) * 8); } while (0)

    const int nt = kend >> 5;
    STAGE(0, 0);
    STAGE(1, 1);

    int aoff[4], boff[4];
#pragma unroll
    for (int m = 0; m < 4; ++m) {
        const int ra = wm + m * 16 + lo;
        const int rb = wn + m * 16 + lo;
        aoff[m] = ra * 32 + ((hi ^ ((ra >> 1) & 3)) * 8);
        boff[m] = rb * 32 + ((hi ^ ((rb >> 1) & 3)) * 8);
    }

    int cur = 0;
    for (int t = 0; t < nt; ++t) {
        __builtin_amdgcn_s_barrier();
        if (t + 2 < nt) {
            int nb = cur + 2; if (nb >= 3) nb -= 3;
            STAGE(t + 2, nb);
            asm volatile("s_waitcnt vmcnt(8)" ::: "memory");
        } else if (t + 1 < nt) {
            asm volatile("s_waitcnt vmcnt(4)" ::: "memory");
        } else {
            asm volatile("s_waitcnt vmcnt(0)" ::: "memory");
        }
        __builtin_amdgcn_s_barrier();
        __builtin_amdgcn_sched_barrier(0);

        short8 av[4], bv[4];
#pragma unroll
        for (int m = 0; m < 4; ++m) av[m] = *(const short8*)&As[cur][aoff[m]];
#pragma unroll
        for (int n = 0; n < 4; ++n) bv[n] = *(const short8*)&Bs[cur][boff[n]];
        asm volatile("s_waitcnt lgkmcnt(0)" ::: "memory");
        __builtin_amdgcn_sched_barrier(0);

        __builtin_amdgcn_s_setprio(1);
#pragma unroll
        for (int m = 0; m < 4; ++m)
#pragma unroll
            for (int n = 0; n < 4; ++n)
                acc[m][n] = MFMA_BF16(av[m], bv[n], acc[m][n], 0, 0, 0);
        __builtin_amdgcn_s_setprio(0);

        cur += 1; if (cur >= 3) cur = 0;
    }
#undef STAGE
}

// V^T via operand swap: C[e][t] = sum_d Wv[e][d] x[t][d]; grid (64 t-blocks, 8 e-blocks).
__global__ __launch_bounds__(256) void v_gemm(const unsigned short* __restrict__ xb,
                                              const unsigned short* __restrict__ wv,
                                              unsigned short* __restrict__ Vt) {
    const int lane = threadIdx.x & 63, wave = threadIdx.x >> 6;
    f32x4 acc[4][4] = {};
    gemm_core(wv, xb, D_DIM, D_DIM, blockIdx.y, blockIdx.x, D_DIM, acc);
    const int rb = blockIdx.y * 128 + (wave >> 1) * 64 + ((lane >> 4) << 2);   // e
    const int cb = blockIdx.x * 128 + (wave & 1) * 64 + (lane & 15);           // t global
#pragma unroll
    for (int m = 0; m < 4; ++m)
#pragma unroll
        for (int n = 0; n < 4; ++n)
#pragma unroll
            for (int r = 0; r < 4; ++r) {
                const int e = rb + m * 16 + r;
                const int t = cb + n * 16;
                Vt[((size_t)(t >> 11) * D_DIM + e) * T_SEQ + (t & 2047)] = f2bf(acc[m][n][r]);
            }
}

// Wave-per-row softmax: 4 rows/block, row in registers, shuffle reductions.
__global__ __launch_bounds__(256) void softmax_kernel(const float* __restrict__ S,
                                                      unsigned short* __restrict__ P) {
    const int lane = threadIdx.x & 63, wave = threadIdx.x >> 6;
    const int row = blockIdx.x * 4 + wave;
    const int b = row >> 11, i = row & 2047;
    const float* srow = S + ((size_t)b * T_SEQ + i) * T_SEQ;
    unsigned short* prow = P + ((size_t)b * T_SEQ + i) * T_SEQ;
    const int len = i + 1;
    const int padlen = ((i >> 7) + 1) * 128;

    f32x4 v[8];
    float m = -1e30f;
#pragma unroll
    for (int c = 0; c < 8; ++c) {
        const int j0 = (c * 64 + lane) * 4;
        if (j0 < padlen) {
            v[c] = *(const f32x4*)(srow + j0);
#pragma unroll
            for (int e = 0; e < 4; ++e)
                if (j0 + e < len) m = fmaxf(m, v[c][e]);
        }
    }
#pragma unroll
    for (int off = 32; off; off >>= 1) m = fmaxf(m, __shfl_xor(m, off, 64));

    float s = 0.f;
#pragma unroll
    for (int c = 0; c < 8; ++c) {
        const int j0 = (c * 64 + lane) * 4;
        if (j0 < padlen) {
#pragma unroll
            for (int e = 0; e < 4; ++e) {
                float ev = (j0 + e < len) ? __expf(v[c][e] - m) : 0.f;
                v[c][e] = ev;
                s += ev;
            }
        }
    }
#pragma unroll
    for (int off = 32; off; off >>= 1) s += __shfl_xor(s, off, 64);
    const float inv = 1.f / s;

#pragma unroll
    for (int c = 0; c < 8; ++c) {
        const int j0 = (c * 64 + lane) * 4;
        if (j0 < padlen) {
            ushort4 o;
            o.x = f2bf(v[c][0] * inv);
            o.y = f2bf(v[c][1] * inv);
            o.z = f2bf(v[c][2] * inv);
            o.w = f2bf(v[c][3] * inv);
            *(ushort4*)(prow + j0) = o;
        }
    }
}

// Flat grid of 512 (all resident at 3 blocks/CU, order-insensitive);
// causal K-bound kend=(bm+1)*128.
__global__ __launch_bounds__(256) void pv_gemm(const unsigned short* __restrict__ P,
                                               const unsigned short* __restrict__ Vt,
                                               float* __restrict__ Out) {
    const int d = blockIdx.x;
    const int j = d & 7;
    const int z = j >> 1;
    const int t = (j & 1) * 64 + (d >> 3);
    const int bm = 15 - (t >> 3), bn = t & 7;

    const unsigned short* Ap = P + (size_t)z * T_SEQ * T_SEQ;
    const unsigned short* Bp = Vt + (size_t)z * D_DIM * T_SEQ;
    f32x4 acc[4][4] = {};
    gemm_core(Ap, Bp, T_SEQ, T_SEQ, bm, bn, (bm + 1) * 128, acc);

    float* Op = Out + (size_t)z * T_SEQ * D_DIM;
    const int lane = threadIdx.x & 63, wave = threadIdx.x >> 6;
    const int rb = bm * 128 + (wave >> 1) * 64 + ((lane >> 4) << 2);
    const int cb = bn * 128 + (wave & 1) * 64 + (lane & 15);
#pragma unroll
    for (int m = 0; m < 4; ++m)
#pragma unroll
        for (int n = 0; n < 4; ++n)
#pragma unroll
            for (int r = 0; r < 4; ++r)
                Op[(size_t)(rb + m * 16 + r) * D_DIM + (cb + n * 16)] = acc[m][n][r];
}

extern "C" void kernel_launch(void* const* d_in, const int* in_sizes, int n_in,
                              void* d_out, int out_size, void* d_ws, size_t ws_size,
                              hipStream_t stream) {
    const float* x  = (const float*)d_in[0];
    const float* Wq = (const float*)d_in[1];
    const float* Wk = (const float*)d_in[2];
    const float* Wv = (const float*)d_in[3];
    float* out = (float*)d_out;
    char* ws = (char*)d_ws;

    unsigned short* xb = (unsigned short*)(ws);                 // 16 MB  x bf16 [8192,1024]
    unsigned short* wb = (unsigned short*)(ws + 16777216);      // 6 MB   Wq|Wk|Wv bf16
    unsigned short* Qb = (unsigned short*)(ws + 23068672);      // 16 MB
    unsigned short* Kb = (unsigned short*)(ws + 39845888);      // 16 MB
    unsigned short* Vt = (unsigned short*)(ws + 56623104);      // 16 MB  V^T per batch [1024][2048]
    float*          S  = (float*)(ws + 73400320);               // 64 MB  scores fp32
    unsigned short* P  = (unsigned short*)(ws + 140509184);     // 32 MB  probs bf16
    (void)ws_size; (void)in_sizes; (void)n_in; (void)out_size;

    cast_kernel<<<8192, 256, 0, stream>>>((const float4*)x, (ushort4*)xb, 2097152);
    cast3_kernel<<<3072, 256, 0, stream>>>((const float4*)Wq, (const float4*)Wk,
                                           (const float4*)Wv, (ushort4*)wb);

    qk_gemm256<<<256, 512, 0, stream>>>(xb, wb, Qb, Kb);
    v_gemm<<<dim3(64, 8), 256, 0, stream>>>(xb, wb + 2097152, Vt);
    s_gemm256<<<144, 512, 0, stream>>>(Qb, Kb, S);
    softmax_kernel<<<2048, 256, 0, stream>>>(S, P);
    pv_gemm<<<512, 256, 0, stream>>>(P, Vt, out);
}